// Round 1
// baseline (689.934 us; speedup 1.0000x reference)
//
#include <hip/hip_runtime.h>
#include <math.h>

// ---------------------------------------------------------------------------
// RoutedAllFC: conv backbone (4x [conv3x3+bias+relu+maxpool2]) -> BN ->
// routed 3-layer expert MLP with per-sample argmax routing.
// Round 1: correct fp32 baseline. Backbone fused per-image in LDS.
// ---------------------------------------------------------------------------

#define IMG_B 4096

// ---------------- backbone: one block per image, 256 threads ----------------
__global__ __launch_bounds__(256, 2) void backbone_kernel(
    const float* __restrict__ x,
    const float* __restrict__ cw1, const float* __restrict__ cb1,
    const float* __restrict__ cw2, const float* __restrict__ cb2,
    const float* __restrict__ cw3, const float* __restrict__ cb3,
    const float* __restrict__ cw4, const float* __restrict__ cb4,
    float* __restrict__ t4)
{
    // LDS layout (region-shared to stay under 64KB static limit):
    //   b1 : [32][18][18] padded, floats 0..10367
    //   rB : floats 10368..14719 (4352 floats)
    //        sx [3][34][34] (3468 f)  -- dead after conv1
    //        b2 [32][10][10] (3200 f) -- written in conv2 (rB re-zeroed first)
    //        b3 [32][6][6]  (1152 f)  -- at rB+3200
    __shared__ float smem[14720];
    float (*b1)[18][18] = reinterpret_cast<float(*)[18][18]>(smem);
    float* rB = smem + 10368;
    float (*sx)[34][34] = reinterpret_cast<float(*)[34][34]>(rB);
    float (*b2)[10][10] = reinterpret_cast<float(*)[10][10]>(rB);
    float (*b3)[6][6]   = reinterpret_cast<float(*)[6][6]>(rB + 3200);

    const int t = threadIdx.x;
    const int b = blockIdx.x;
    const int lane = t & 63;
    const int ocb = __builtin_amdgcn_readfirstlane(t >> 6) << 3;  // wave's 8-oc group

    // zero everything (halos must be 0)
    for (int i = t; i < 14720; i += 256) smem[i] = 0.f;
    __syncthreads();

    // load image into padded sx
    {
        const float* xb = x + (size_t)b * 3072;
        for (int i = t; i < 3072; i += 256) {
            int ic = i >> 10, r = i & 1023;
            sx[ic][(r >> 5) + 1][(r & 31) + 1] = xb[i];
        }
    }
    __syncthreads();

    // ---- conv1: 3->32, 32x32, relu, pool -> b1[32][16][16] ----
    {
        float bias[8];
        #pragma unroll
        for (int o = 0; o < 8; ++o) bias[o] = cb1[ocb + o];
        for (int q = 0; q < 4; ++q) {
            const int id = (q << 6) | lane;       // pooled pixel 0..255
            const int py = id >> 4, px = id & 15;
            float acc[2][2][8];
            #pragma unroll
            for (int sy = 0; sy < 2; ++sy)
                #pragma unroll
                for (int sxx = 0; sxx < 2; ++sxx)
                    #pragma unroll
                    for (int o = 0; o < 8; ++o) acc[sy][sxx][o] = bias[o];
            #pragma unroll
            for (int ic = 0; ic < 3; ++ic) {
                float wn[4][4];
                #pragma unroll
                for (int wy = 0; wy < 4; ++wy)
                    #pragma unroll
                    for (int wx = 0; wx < 4; ++wx)
                        wn[wy][wx] = sx[ic][2 * py + wy][2 * px + wx];
                #pragma unroll
                for (int o = 0; o < 8; ++o) {
                    #pragma unroll
                    for (int dy = 0; dy < 3; ++dy)
                        #pragma unroll
                        for (int dx = 0; dx < 3; ++dx) {
                            const float w = cw1[(ocb + o) * 27 + ic * 9 + dy * 3 + dx];
                            #pragma unroll
                            for (int sy = 0; sy < 2; ++sy)
                                #pragma unroll
                                for (int sxx = 0; sxx < 2; ++sxx)
                                    acc[sy][sxx][o] = fmaf(w, wn[sy + dy][sxx + dx], acc[sy][sxx][o]);
                        }
                }
            }
            #pragma unroll
            for (int o = 0; o < 8; ++o) {
                float m = fmaxf(fmaxf(acc[0][0][o], acc[0][1][o]),
                                fmaxf(acc[1][0][o], acc[1][1][o]));
                b1[ocb + o][py + 1][px + 1] = fmaxf(m, 0.f);
            }
        }
    }
    __syncthreads();

    // re-zero region B (sx is dead; b2/b3 halos must be 0)
    for (int i = t; i < 4352; i += 256) rB[i] = 0.f;
    __syncthreads();

    // ---- conv2: 32->32, 16x16, relu, pool -> b2[32][8][8] ----
    {
        const int py = lane >> 3, px = lane & 7;   // pooled pixel 0..63
        float acc[2][2][8];
        #pragma unroll
        for (int sy = 0; sy < 2; ++sy)
            #pragma unroll
            for (int sxx = 0; sxx < 2; ++sxx)
                #pragma unroll
                for (int o = 0; o < 8; ++o) acc[sy][sxx][o] = cb2[ocb + o];
        for (int ic = 0; ic < 32; ++ic) {
            float wn[4][4];
            #pragma unroll
            for (int wy = 0; wy < 4; ++wy)
                #pragma unroll
                for (int wx = 0; wx < 4; ++wx)
                    wn[wy][wx] = b1[ic][2 * py + wy][2 * px + wx];
            #pragma unroll
            for (int o = 0; o < 8; ++o) {
                #pragma unroll
                for (int dy = 0; dy < 3; ++dy)
                    #pragma unroll
                    for (int dx = 0; dx < 3; ++dx) {
                        const float w = cw2[((ocb + o) * 32 + ic) * 9 + dy * 3 + dx];
                        #pragma unroll
                        for (int sy = 0; sy < 2; ++sy)
                            #pragma unroll
                            for (int sxx = 0; sxx < 2; ++sxx)
                                acc[sy][sxx][o] = fmaf(w, wn[sy + dy][sxx + dx], acc[sy][sxx][o]);
                    }
            }
        }
        #pragma unroll
        for (int o = 0; o < 8; ++o) {
            float m = fmaxf(fmaxf(acc[0][0][o], acc[0][1][o]),
                            fmaxf(acc[1][0][o], acc[1][1][o]));
            b2[ocb + o][py + 1][px + 1] = fmaxf(m, 0.f);
        }
    }
    __syncthreads();

    // ---- conv3: 32->32, 8x8, relu, pool -> b3[32][4][4] ----
    {
        const int y = lane >> 3, xx = lane & 7;    // pre-pool pixel
        float acc[8];
        #pragma unroll
        for (int o = 0; o < 8; ++o) acc[o] = cb3[ocb + o];
        for (int ic = 0; ic < 32; ++ic) {
            float wn[3][3];
            #pragma unroll
            for (int dy = 0; dy < 3; ++dy)
                #pragma unroll
                for (int dx = 0; dx < 3; ++dx)
                    wn[dy][dx] = b2[ic][y + dy][xx + dx];
            #pragma unroll
            for (int o = 0; o < 8; ++o)
                #pragma unroll
                for (int dy = 0; dy < 3; ++dy)
                    #pragma unroll
                    for (int dx = 0; dx < 3; ++dx)
                        acc[o] = fmaf(cw3[((ocb + o) * 32 + ic) * 9 + dy * 3 + dx],
                                      wn[dy][dx], acc[o]);
        }
        #pragma unroll
        for (int o = 0; o < 8; ++o) {
            float v = fmaxf(acc[o], 0.f);
            v = fmaxf(v, __shfl_xor(v, 1));
            v = fmaxf(v, __shfl_xor(v, 8));
            if (((xx | y) & 1) == 0)
                b3[ocb + o][(y >> 1) + 1][(xx >> 1) + 1] = v;
        }
    }
    __syncthreads();

    // ---- conv4: 32->32, 4x4, relu, pool -> t4[b][32][2][2] (global) ----
    if (lane < 16) {
        const int y = lane >> 2, xx = lane & 3;    // pre-pool pixel
        float acc[8];
        #pragma unroll
        for (int o = 0; o < 8; ++o) acc[o] = cb4[ocb + o];
        for (int ic = 0; ic < 32; ++ic) {
            float wn[3][3];
            #pragma unroll
            for (int dy = 0; dy < 3; ++dy)
                #pragma unroll
                for (int dx = 0; dx < 3; ++dx)
                    wn[dy][dx] = b3[ic][y + dy][xx + dx];
            #pragma unroll
            for (int o = 0; o < 8; ++o)
                #pragma unroll
                for (int dy = 0; dy < 3; ++dy)
                    #pragma unroll
                    for (int dx = 0; dx < 3; ++dx)
                        acc[o] = fmaf(cw4[((ocb + o) * 32 + ic) * 9 + dy * 3 + dx],
                                      wn[dy][dx], acc[o]);
        }
        #pragma unroll
        for (int o = 0; o < 8; ++o) {
            float v = fmaxf(acc[o], 0.f);
            v = fmaxf(v, __shfl_xor(v, 1));
            v = fmaxf(v, __shfl_xor(v, 4));
            if (((xx | y) & 1) == 0)
                t4[(size_t)b * 128 + (ocb + o) * 4 + (y >> 1) * 2 + (xx >> 1)] = v;
        }
    }
}

// ---------------- BN batch stats: one block per channel ----------------
__global__ __launch_bounds__(256) void bnstats_kernel(
    const float* __restrict__ t4, float* __restrict__ mus, float* __restrict__ rss)
{
    __shared__ double ssum[256];
    __shared__ double ssq[256];
    const int c = blockIdx.x, t = threadIdx.x;
    double s = 0.0, q = 0.0;
    for (int j = t; j < 16384; j += 256) {
        float v = t4[(size_t)(j >> 2) * 128 + c * 4 + (j & 3)];
        s += (double)v;
        q += (double)v * (double)v;
    }
    ssum[t] = s; ssq[t] = q;
    __syncthreads();
    for (int w = 128; w > 0; w >>= 1) {
        if (t < w) { ssum[t] += ssum[t + w]; ssq[t] += ssq[t + w]; }
        __syncthreads();
    }
    if (t == 0) {
        double mu = ssum[0] / 16384.0;
        double var = ssq[0] / 16384.0 - mu * mu;
        mus[c] = (float)mu;
        rss[c] = (float)(1.0 / sqrt(var + 1e-5));
    }
}

// ---------------- routing + expert MLP: one block (1 wave) per sample ------
__global__ __launch_bounds__(64) void routing_kernel(
    const float* __restrict__ t4, const float* __restrict__ mus,
    const float* __restrict__ rss,
    const float* __restrict__ bng, const float* __restrict__ bnb,
    const float* __restrict__ wpt, const float* __restrict__ wd1,
    const float* __restrict__ wd2, const float* __restrict__ wd3,
    const float* __restrict__ s1w, const float* __restrict__ s1b,
    const float* __restrict__ s2w, const float* __restrict__ s2b,
    const float* __restrict__ s3w, const float* __restrict__ s3b,
    float* __restrict__ out)
{
    __shared__ float f[128];
    __shared__ float h1s[48];
    __shared__ float h2s[48];
    __shared__ float tmp[16];
    __shared__ int act;
    const int t = threadIdx.x, b = blockIdx.x;

    for (int i = t; i < 128; i += 64) {
        int c = i >> 2;
        float v = t4[(size_t)b * 128 + i];
        f[i] = (v - mus[c]) * rss[c] * bng[c] + bnb[c];
    }
    __syncthreads();

    // task assignment: argmax over 10 agents (fp64 accumulate for stability)
    if (t < 10) {
        double a = 0.0;
        for (int k = 0; k < 128; ++k) a = fma((double)f[k], (double)wpt[k * 10 + t], a);
        tmp[t] = (float)a;
    }
    __syncthreads();
    if (t == 0) {
        int bi = 0; float bv = tmp[0];
        for (int i = 1; i < 10; ++i) if (tmp[i] > bv) { bv = tmp[i]; bi = i; }
        act = bi;
    }
    __syncthreads();
    const int agent = act;

    // decision 1 (argmax over 16 modules)
    if (t < 16) {
        double a = 0.0;
        const float* w = wd1 + (size_t)agent * 128 * 16 + t;
        for (int k = 0; k < 128; ++k) a = fma((double)f[k], (double)w[k * 16], a);
        tmp[t] = (float)a;
    }
    __syncthreads();
    if (t == 0) {
        int bi = 0; float bv = tmp[0];
        for (int i = 1; i < 16; ++i) if (tmp[i] > bv) { bv = tmp[i]; bi = i; }
        act = bi;
    }
    __syncthreads();
    const int a1 = act;

    // expert layer 1: 128 -> 48, relu
    if (t < 48) {
        float a = s1b[a1 * 48 + t];
        const float* w = s1w + (size_t)a1 * 128 * 48 + t;
        for (int k = 0; k < 128; ++k) a = fmaf(f[k], w[k * 48], a);
        h1s[t] = fmaxf(a, 0.f);
    }
    __syncthreads();

    // decision 2
    if (t < 16) {
        double a = 0.0;
        const float* w = wd2 + (size_t)agent * 48 * 16 + t;
        for (int k = 0; k < 48; ++k) a = fma((double)h1s[k], (double)w[k * 16], a);
        tmp[t] = (float)a;
    }
    __syncthreads();
    if (t == 0) {
        int bi = 0; float bv = tmp[0];
        for (int i = 1; i < 16; ++i) if (tmp[i] > bv) { bv = tmp[i]; bi = i; }
        act = bi;
    }
    __syncthreads();
    const int a2 = act;

    // expert layer 2: 48 -> 48, relu
    if (t < 48) {
        float a = s2b[a2 * 48 + t];
        const float* w = s2w + (size_t)a2 * 48 * 48 + t;
        for (int k = 0; k < 48; ++k) a = fmaf(h1s[k], w[k * 48], a);
        h2s[t] = fmaxf(a, 0.f);
    }
    __syncthreads();

    // decision 3
    if (t < 16) {
        double a = 0.0;
        const float* w = wd3 + (size_t)agent * 48 * 16 + t;
        for (int k = 0; k < 48; ++k) a = fma((double)h2s[k], (double)w[k * 16], a);
        tmp[t] = (float)a;
    }
    __syncthreads();
    if (t == 0) {
        int bi = 0; float bv = tmp[0];
        for (int i = 1; i < 16; ++i) if (tmp[i] > bv) { bv = tmp[i]; bi = i; }
        act = bi;
    }
    __syncthreads();
    const int a3 = act;

    // expert layer 3: 48 -> 10, no relu
    if (t < 10) {
        float a = s3b[a3 * 10 + t];
        const float* w = s3w + (size_t)a3 * 48 * 10 + t;
        for (int k = 0; k < 48; ++k) a = fmaf(h2s[k], w[k * 10], a);
        out[(size_t)b * 10 + t] = a;
    }
}

// ---------------------------------------------------------------------------
extern "C" void kernel_launch(void* const* d_in, const int* in_sizes, int n_in,
                              void* d_out, int out_size, void* d_ws, size_t ws_size,
                              hipStream_t stream)
{
    (void)in_sizes; (void)n_in; (void)out_size; (void)ws_size;

    const float* x   = (const float*)d_in[0];
    // d_in[1] = tasks (unused by the reference computation)
    const float* cw1 = (const float*)d_in[2];
    const float* cb1 = (const float*)d_in[3];
    const float* cw2 = (const float*)d_in[4];
    const float* cb2 = (const float*)d_in[5];
    const float* cw3 = (const float*)d_in[6];
    const float* cb3 = (const float*)d_in[7];
    const float* cw4 = (const float*)d_in[8];
    const float* cb4 = (const float*)d_in[9];
    const float* bng = (const float*)d_in[10];
    const float* bnb = (const float*)d_in[11];
    const float* wpt = (const float*)d_in[12];
    const float* wd1 = (const float*)d_in[13];
    const float* wd2 = (const float*)d_in[14];
    const float* wd3 = (const float*)d_in[15];
    const float* s1w = (const float*)d_in[16];
    const float* s1b = (const float*)d_in[17];
    const float* s2w = (const float*)d_in[18];
    const float* s2b = (const float*)d_in[19];
    const float* s3w = (const float*)d_in[20];
    const float* s3b = (const float*)d_in[21];
    float* out = (float*)d_out;

    float* t4  = (float*)d_ws;           // [4096][128] post-conv4 features
    float* mus = t4 + (size_t)IMG_B * 128;
    float* rss = mus + 32;

    hipLaunchKernelGGL(backbone_kernel, dim3(IMG_B), dim3(256), 0, stream,
                       x, cw1, cb1, cw2, cb2, cw3, cb3, cw4, cb4, t4);
    hipLaunchKernelGGL(bnstats_kernel, dim3(32), dim3(256), 0, stream, t4, mus, rss);
    hipLaunchKernelGGL(routing_kernel, dim3(IMG_B), dim3(64), 0, stream,
                       t4, mus, rss, bng, bnb, wpt, wd1, wd2, wd3,
                       s1w, s1b, s2w, s2b, s3w, s3b, out);
}

// Round 2
// 506.493 us; speedup vs baseline: 1.3622x; 1.3622x over previous
//
#include <hip/hip_runtime.h>
#include <math.h>

// ---------------------------------------------------------------------------
// RoutedAllFC round 2: fp32 backbone, occupancy-optimized.
//  - LDS 49.5KB/block -> 3 blocks/CU (was 58.9KB -> 2)
//  - weights pre-transposed to ic-major [ic][oc][9] -> contiguous s_load_dwordx16
//  - float2 LDS window reads (ds_read_b64)
//  - conv4 uses all 64 lanes (16 px x 4 oc-pair groups)
// ---------------------------------------------------------------------------

#define IMG_B 4096

// ---- weight transpose pre-pass: [oc][ic][9] -> [ic][oc][9] ----------------
__global__ __launch_bounds__(256) void twt_kernel(
    const float* __restrict__ cw1, const float* __restrict__ cw2,
    const float* __restrict__ cw3, const float* __restrict__ cw4,
    float* __restrict__ w1t, float* __restrict__ w2t,
    float* __restrict__ w3t, float* __restrict__ w4t)
{
    const int i = blockIdx.x * 256 + threadIdx.x;
    if (i < 9216) {
        const int k = i % 9, r = i / 9;       // r = ic*32 + oc
        const int oc = r & 31, ic = r >> 5;
        w2t[i] = cw2[(oc * 32 + ic) * 9 + k];
        w3t[i] = cw3[(oc * 32 + ic) * 9 + k];
        w4t[i] = cw4[(oc * 32 + ic) * 9 + k];
        if (i < 864) {                         // ic<3 here: r>>5 in 0..2
            w1t[i] = cw1[(oc * 3 + ic) * 9 + k];
        }
    }
}

// ---------------- backbone: one block per image, 256 threads ----------------
// LDS: b1 [32][16][18] (9216 f, col-halo only) | region B (3468 f):
//      sx [3][34][34] (conv1 input, padded) -> b2 [32][8][8] + b3 [32][4][4]
__global__ __launch_bounds__(256, 3) void backbone_kernel(
    const float* __restrict__ x,
    const float* __restrict__ w1t, const float* __restrict__ cb1,
    const float* __restrict__ w2t, const float* __restrict__ cb2,
    const float* __restrict__ w3t, const float* __restrict__ cb3,
    const float* __restrict__ w4t, const float* __restrict__ cb4,
    float* __restrict__ t4)
{
    __shared__ float smem[12684];
    float (*b1)[16][18] = reinterpret_cast<float(*)[16][18]>(smem);
    float* rB = smem + 9216;
    float (*sx)[34][34] = reinterpret_cast<float(*)[34][34]>(rB);
    float (*b2)[8][8]   = reinterpret_cast<float(*)[8][8]>(rB);
    float (*b3)[4][4]   = reinterpret_cast<float(*)[4][4]>(rB + 2048);

    const int t = threadIdx.x;
    const int b = blockIdx.x;
    const int lane = t & 63;
    const int ocb = __builtin_amdgcn_readfirstlane(t >> 6) << 3;  // wave's 8-oc group

    // zero all LDS once (sx halos + b1 col-halos must be 0)
    for (int i = t; i < 12684; i += 256) smem[i] = 0.f;
    __syncthreads();

    // load image into padded sx
    {
        const float* xb = x + (size_t)b * 3072;
        for (int i = t; i < 3072; i += 256) {
            int ic = i >> 10, r = i & 1023;
            sx[ic][(r >> 5) + 1][(r & 31) + 1] = xb[i];
        }
    }
    __syncthreads();

    // ---- conv1: 3->32, 32x32, relu, pool -> b1[32][16][1..16] ----
    {
        float bias[8];
        #pragma unroll
        for (int o = 0; o < 8; ++o) bias[o] = cb1[ocb + o];
        for (int q = 0; q < 4; ++q) {
            const int id = (q << 6) | lane;       // pooled pixel 0..255
            const int py = id >> 4, px = id & 15;
            float acc[2][2][8];
            #pragma unroll
            for (int sy = 0; sy < 2; ++sy)
                #pragma unroll
                for (int sxx = 0; sxx < 2; ++sxx)
                    #pragma unroll
                    for (int o = 0; o < 8; ++o) acc[sy][sxx][o] = bias[o];
            #pragma unroll
            for (int ic = 0; ic < 3; ++ic) {
                float wn[4][4];
                #pragma unroll
                for (int wy = 0; wy < 4; ++wy) {
                    const float2* rp = reinterpret_cast<const float2*>(&sx[ic][2 * py + wy][2 * px]);
                    float2 lo = rp[0], hi = rp[1];
                    wn[wy][0] = lo.x; wn[wy][1] = lo.y;
                    wn[wy][2] = hi.x; wn[wy][3] = hi.y;
                }
                const float* w = w1t + (ic * 32 + ocb) * 9;
                #pragma unroll
                for (int o = 0; o < 8; ++o) {
                    #pragma unroll
                    for (int dy = 0; dy < 3; ++dy)
                        #pragma unroll
                        for (int dx = 0; dx < 3; ++dx) {
                            const float wv = w[o * 9 + dy * 3 + dx];
                            #pragma unroll
                            for (int sy = 0; sy < 2; ++sy)
                                #pragma unroll
                                for (int sxx = 0; sxx < 2; ++sxx)
                                    acc[sy][sxx][o] = fmaf(wv, wn[sy + dy][sxx + dx], acc[sy][sxx][o]);
                        }
                }
            }
            #pragma unroll
            for (int o = 0; o < 8; ++o) {
                float m = fmaxf(fmaxf(acc[0][0][o], acc[0][1][o]),
                                fmaxf(acc[1][0][o], acc[1][1][o]));
                b1[ocb + o][py][px + 1] = fmaxf(m, 0.f);
            }
        }
    }
    __syncthreads();

    // ---- conv2: 32->32, 16x16, relu, pool -> b2[32][8][8] (unpadded) ----
    {
        const int py = lane >> 3, px = lane & 7;   // pooled pixel 0..63
        int rr[4]; bool rok[4];
        #pragma unroll
        for (int wy = 0; wy < 4; ++wy) {
            int r = 2 * py + wy - 1;               // real row in [-1,16]
            rok[wy] = ((unsigned)r < 16u);
            rr[wy] = r & 15;
        }
        float acc[2][2][8];
        #pragma unroll
        for (int sy = 0; sy < 2; ++sy)
            #pragma unroll
            for (int sxx = 0; sxx < 2; ++sxx)
                #pragma unroll
                for (int o = 0; o < 8; ++o) acc[sy][sxx][o] = cb2[ocb + o];
        for (int ic = 0; ic < 32; ++ic) {
            float wn[4][4];
            #pragma unroll
            for (int wy = 0; wy < 4; ++wy) {
                const float2* rp = reinterpret_cast<const float2*>(&b1[ic][rr[wy]][2 * px]);
                float2 lo = rp[0], hi = rp[1];
                wn[wy][0] = rok[wy] ? lo.x : 0.f;
                wn[wy][1] = rok[wy] ? lo.y : 0.f;
                wn[wy][2] = rok[wy] ? hi.x : 0.f;
                wn[wy][3] = rok[wy] ? hi.y : 0.f;
            }
            const float* w = w2t + (ic * 32 + ocb) * 9;   // 72 contiguous floats
            #pragma unroll
            for (int o = 0; o < 8; ++o) {
                #pragma unroll
                for (int dy = 0; dy < 3; ++dy)
                    #pragma unroll
                    for (int dx = 0; dx < 3; ++dx) {
                        const float wv = w[o * 9 + dy * 3 + dx];
                        #pragma unroll
                        for (int sy = 0; sy < 2; ++sy)
                            #pragma unroll
                            for (int sxx = 0; sxx < 2; ++sxx)
                                acc[sy][sxx][o] = fmaf(wv, wn[sy + dy][sxx + dx], acc[sy][sxx][o]);
                    }
            }
        }
        __syncthreads();  // b1 reads done before b2 (aliased with nothing) write; sx dead
        #pragma unroll
        for (int o = 0; o < 8; ++o) {
            float m = fmaxf(fmaxf(acc[0][0][o], acc[0][1][o]),
                            fmaxf(acc[1][0][o], acc[1][1][o]));
            b2[ocb + o][py][px] = fmaxf(m, 0.f);
        }
    }
    __syncthreads();

    // ---- conv3: 32->32, 8x8, relu, pool -> b3[32][4][4] (unpadded) ----
    {
        const int y = lane >> 3, xx = lane & 7;    // pre-pool pixel
        int ri[3], ci[3]; bool rok[3], cok[3];
        #pragma unroll
        for (int d = 0; d < 3; ++d) {
            int r = y + d - 1;  rok[d] = ((unsigned)r < 8u);  ri[d] = r & 7;
            int c = xx + d - 1; cok[d] = ((unsigned)c < 8u);  ci[d] = c & 7;
        }
        float acc[8];
        #pragma unroll
        for (int o = 0; o < 8; ++o) acc[o] = cb3[ocb + o];
        for (int ic = 0; ic < 32; ++ic) {
            float wn[3][3];
            #pragma unroll
            for (int dy = 0; dy < 3; ++dy)
                #pragma unroll
                for (int dx = 0; dx < 3; ++dx)
                    wn[dy][dx] = (rok[dy] && cok[dx]) ? b2[ic][ri[dy]][ci[dx]] : 0.f;
            const float* w = w3t + (ic * 32 + ocb) * 9;
            #pragma unroll
            for (int o = 0; o < 8; ++o)
                #pragma unroll
                for (int dy = 0; dy < 3; ++dy)
                    #pragma unroll
                    for (int dx = 0; dx < 3; ++dx)
                        acc[o] = fmaf(w[o * 9 + dy * 3 + dx], wn[dy][dx], acc[o]);
        }
        #pragma unroll
        for (int o = 0; o < 8; ++o) {
            float v = fmaxf(acc[o], 0.f);
            v = fmaxf(v, __shfl_xor(v, 1));
            v = fmaxf(v, __shfl_xor(v, 8));
            if (((xx | y) & 1) == 0)
                b3[ocb + o][y >> 1][xx >> 1] = v;
        }
    }
    __syncthreads();

    // ---- conv4: 32->32, 4x4, relu, pool -> t4[b][32][2][2]; all 64 lanes ----
    {
        const int g  = lane >> 4;          // oc-pair group 0..3
        const int yy = (lane >> 2) & 3;    // pre-pool row
        const int xx = lane & 3;           // pre-pool col
        int ri[3], ci[3]; bool rok[3], cok[3];
        #pragma unroll
        for (int d = 0; d < 3; ++d) {
            int r = yy + d - 1; rok[d] = ((unsigned)r < 4u); ri[d] = r & 3;
            int c = xx + d - 1; cok[d] = ((unsigned)c < 4u); ci[d] = c & 3;
        }
        const int oc0 = ocb + 2 * g;
        float acc0 = cb4[oc0], acc1 = cb4[oc0 + 1];
        for (int ic = 0; ic < 32; ++ic) {
            float wn[3][3];
            #pragma unroll
            for (int dy = 0; dy < 3; ++dy)
                #pragma unroll
                for (int dx = 0; dx < 3; ++dx)
                    wn[dy][dx] = (rok[dy] && cok[dx]) ? b3[ic][ri[dy]][ci[dx]] : 0.f;
            const float* w = w4t + (ic * 32 + oc0) * 9;   // per-lane (vector) load
            #pragma unroll
            for (int dy = 0; dy < 3; ++dy)
                #pragma unroll
                for (int dx = 0; dx < 3; ++dx) {
                    acc0 = fmaf(w[dy * 3 + dx],     wn[dy][dx], acc0);
                    acc1 = fmaf(w[9 + dy * 3 + dx], wn[dy][dx], acc1);
                }
        }
        float v0 = fmaxf(acc0, 0.f), v1 = fmaxf(acc1, 0.f);
        v0 = fmaxf(v0, __shfl_xor(v0, 1)); v0 = fmaxf(v0, __shfl_xor(v0, 4));
        v1 = fmaxf(v1, __shfl_xor(v1, 1)); v1 = fmaxf(v1, __shfl_xor(v1, 4));
        if (((xx | yy) & 1) == 0) {
            const int py = yy >> 1, px = xx >> 1;
            t4[(size_t)b * 128 + oc0 * 4 + py * 2 + px] = v0;
            t4[(size_t)b * 128 + (oc0 + 1) * 4 + py * 2 + px] = v1;
        }
    }
}

// ---------------- BN batch stats: one block per channel ----------------
__global__ __launch_bounds__(256) void bnstats_kernel(
    const float* __restrict__ t4, float* __restrict__ mus, float* __restrict__ rss)
{
    __shared__ double ssum[256];
    __shared__ double ssq[256];
    const int c = blockIdx.x, t = threadIdx.x;
    double s = 0.0, q = 0.0;
    for (int j = t; j < 16384; j += 256) {
        float v = t4[(size_t)(j >> 2) * 128 + c * 4 + (j & 3)];
        s += (double)v;
        q += (double)v * (double)v;
    }
    ssum[t] = s; ssq[t] = q;
    __syncthreads();
    for (int w = 128; w > 0; w >>= 1) {
        if (t < w) { ssum[t] += ssum[t + w]; ssq[t] += ssq[t + w]; }
        __syncthreads();
    }
    if (t == 0) {
        double mu = ssum[0] / 16384.0;
        double var = ssq[0] / 16384.0 - mu * mu;
        mus[c] = (float)mu;
        rss[c] = (float)(1.0 / sqrt(var + 1e-5));
    }
}

// ---------------- routing + expert MLP: one block (1 wave) per sample ------
__global__ __launch_bounds__(64) void routing_kernel(
    const float* __restrict__ t4, const float* __restrict__ mus,
    const float* __restrict__ rss,
    const float* __restrict__ bng, const float* __restrict__ bnb,
    const float* __restrict__ wpt, const float* __restrict__ wd1,
    const float* __restrict__ wd2, const float* __restrict__ wd3,
    const float* __restrict__ s1w, const float* __restrict__ s1b,
    const float* __restrict__ s2w, const float* __restrict__ s2b,
    const float* __restrict__ s3w, const float* __restrict__ s3b,
    float* __restrict__ out)
{
    __shared__ float f[128];
    __shared__ float h1s[48];
    __shared__ float h2s[48];
    __shared__ float tmp[16];
    __shared__ int act;
    const int t = threadIdx.x, b = blockIdx.x;

    for (int i = t; i < 128; i += 64) {
        int c = i >> 2;
        float v = t4[(size_t)b * 128 + i];
        f[i] = (v - mus[c]) * rss[c] * bng[c] + bnb[c];
    }
    __syncthreads();

    // task assignment: argmax over 10 agents (fp64 accumulate for stability)
    if (t < 10) {
        double a = 0.0;
        for (int k = 0; k < 128; ++k) a = fma((double)f[k], (double)wpt[k * 10 + t], a);
        tmp[t] = (float)a;
    }
    __syncthreads();
    if (t == 0) {
        int bi = 0; float bv = tmp[0];
        for (int i = 1; i < 10; ++i) if (tmp[i] > bv) { bv = tmp[i]; bi = i; }
        act = bi;
    }
    __syncthreads();
    const int agent = act;

    // decision 1 (argmax over 16 modules)
    if (t < 16) {
        double a = 0.0;
        const float* w = wd1 + (size_t)agent * 128 * 16 + t;
        for (int k = 0; k < 128; ++k) a = fma((double)f[k], (double)w[k * 16], a);
        tmp[t] = (float)a;
    }
    __syncthreads();
    if (t == 0) {
        int bi = 0; float bv = tmp[0];
        for (int i = 1; i < 16; ++i) if (tmp[i] > bv) { bv = tmp[i]; bi = i; }
        act = bi;
    }
    __syncthreads();
    const int a1 = act;

    // expert layer 1: 128 -> 48, relu
    if (t < 48) {
        float a = s1b[a1 * 48 + t];
        const float* w = s1w + (size_t)a1 * 128 * 48 + t;
        for (int k = 0; k < 128; ++k) a = fmaf(f[k], w[k * 48], a);
        h1s[t] = fmaxf(a, 0.f);
    }
    __syncthreads();

    // decision 2
    if (t < 16) {
        double a = 0.0;
        const float* w = wd2 + (size_t)agent * 48 * 16 + t;
        for (int k = 0; k < 48; ++k) a = fma((double)h1s[k], (double)w[k * 16], a);
        tmp[t] = (float)a;
    }
    __syncthreads();
    if (t == 0) {
        int bi = 0; float bv = tmp[0];
        for (int i = 1; i < 16; ++i) if (tmp[i] > bv) { bv = tmp[i]; bi = i; }
        act = bi;
    }
    __syncthreads();
    const int a2 = act;

    // expert layer 2: 48 -> 48, relu
    if (t < 48) {
        float a = s2b[a2 * 48 + t];
        const float* w = s2w + (size_t)a2 * 48 * 48 + t;
        for (int k = 0; k < 48; ++k) a = fmaf(h1s[k], w[k * 48], a);
        h2s[t] = fmaxf(a, 0.f);
    }
    __syncthreads();

    // decision 3
    if (t < 16) {
        double a = 0.0;
        const float* w = wd3 + (size_t)agent * 48 * 16 + t;
        for (int k = 0; k < 48; ++k) a = fma((double)h2s[k], (double)w[k * 16], a);
        tmp[t] = (float)a;
    }
    __syncthreads();
    if (t == 0) {
        int bi = 0; float bv = tmp[0];
        for (int i = 1; i < 16; ++i) if (tmp[i] > bv) { bv = tmp[i]; bi = i; }
        act = bi;
    }
    __syncthreads();
    const int a3 = act;

    // expert layer 3: 48 -> 10, no relu
    if (t < 10) {
        float a = s3b[a3 * 10 + t];
        const float* w = s3w + (size_t)a3 * 48 * 10 + t;
        for (int k = 0; k < 48; ++k) a = fmaf(h2s[k], w[k * 10], a);
        out[(size_t)b * 10 + t] = a;
    }
}

// ---------------------------------------------------------------------------
extern "C" void kernel_launch(void* const* d_in, const int* in_sizes, int n_in,
                              void* d_out, int out_size, void* d_ws, size_t ws_size,
                              hipStream_t stream)
{
    (void)in_sizes; (void)n_in; (void)out_size; (void)ws_size;

    const float* x   = (const float*)d_in[0];
    // d_in[1] = tasks (unused by the reference computation)
    const float* cw1 = (const float*)d_in[2];
    const float* cb1 = (const float*)d_in[3];
    const float* cw2 = (const float*)d_in[4];
    const float* cb2 = (const float*)d_in[5];
    const float* cw3 = (const float*)d_in[6];
    const float* cb3 = (const float*)d_in[7];
    const float* cw4 = (const float*)d_in[8];
    const float* cb4 = (const float*)d_in[9];
    const float* bng = (const float*)d_in[10];
    const float* bnb = (const float*)d_in[11];
    const float* wpt = (const float*)d_in[12];
    const float* wd1 = (const float*)d_in[13];
    const float* wd2 = (const float*)d_in[14];
    const float* wd3 = (const float*)d_in[15];
    const float* s1w = (const float*)d_in[16];
    const float* s1b = (const float*)d_in[17];
    const float* s2w = (const float*)d_in[18];
    const float* s2b = (const float*)d_in[19];
    const float* s3w = (const float*)d_in[20];
    const float* s3b = (const float*)d_in[21];
    float* out = (float*)d_out;

    float* t4  = (float*)d_ws;                      // [4096][128]
    float* mus = t4 + (size_t)IMG_B * 128;          // 32
    float* rss = mus + 32;                          // 32
    float* w1t = rss + 32;                          // 864
    float* w2t = w1t + 864;                         // 9216
    float* w3t = w2t + 9216;                        // 9216
    float* w4t = w3t + 9216;                        // 9216

    hipLaunchKernelGGL(twt_kernel, dim3(36), dim3(256), 0, stream,
                       cw1, cw2, cw3, cw4, w1t, w2t, w3t, w4t);
    hipLaunchKernelGGL(backbone_kernel, dim3(IMG_B), dim3(256), 0, stream,
                       x, w1t, cb1, w2t, cb2, w3t, cb3, w4t, cb4, t4);
    hipLaunchKernelGGL(bnstats_kernel, dim3(32), dim3(256), 0, stream, t4, mus, rss);
    hipLaunchKernelGGL(routing_kernel, dim3(IMG_B), dim3(64), 0, stream,
                       t4, mus, rss, bng, bnb, wpt, wd1, wd2, wd3,
                       s1w, s1b, s2w, s2b, s3w, s3b, out);
}

// Round 3
// 282.196 us; speedup vs baseline: 2.4449x; 1.7948x over previous
//
#include <hip/hip_runtime.h>
#include <math.h>

// ---------------------------------------------------------------------------
// RoutedAllFC round 3: conv2 + conv3 on MFMA (fp16 2-way-split, 3 products =
// fp32-level accuracy), conv1/conv4 remain fp32 VALU. Per-image fused block.
// ---------------------------------------------------------------------------

#define IMG_B 4096

typedef _Float16 f16x8 __attribute__((ext_vector_type(8)));
typedef _Float16 f16x4 __attribute__((ext_vector_type(4)));
typedef float    f32x4 __attribute__((ext_vector_type(4)));

__device__ inline f16x8 f16x8_zero() {
    f16x8 z;
    #pragma unroll
    for (int i = 0; i < 8; ++i) z[i] = (_Float16)0.f;
    return z;
}

// ---- weight prep: fp32 ic-major for conv1/conv4; fp16 h/l split for conv2/3
// w2s/w3s layout: [tap][part(h=0,l=1)][oc(32)][ic(32)] fp16
__global__ __launch_bounds__(256) void twt_kernel(
    const float* __restrict__ cw1, const float* __restrict__ cw2,
    const float* __restrict__ cw3, const float* __restrict__ cw4,
    float* __restrict__ w1t, float* __restrict__ w4t,
    _Float16* __restrict__ w2s, _Float16* __restrict__ w3s)
{
    const int i = blockIdx.x * 256 + threadIdx.x;
    if (i < 9216) {
        const int k = i % 9, r = i / 9;        // r = ic*32 + oc  (fp32 path)
        const int oc = r & 31, ic = r >> 5;
        w4t[i] = cw4[(oc * 32 + ic) * 9 + k];
        if (i < 864) w1t[i] = cw1[(oc * 3 + ic) * 9 + k];

        // fp16 split path: decode r as oc2*32+ic2
        const int ic2 = r & 31, oc2 = r >> 5;
        {
            float w = cw2[(oc2 * 32 + ic2) * 9 + k];
            _Float16 h = (_Float16)w;
            _Float16 l = (_Float16)(w - (float)h);
            w2s[(k * 2 + 0) * 1024 + oc2 * 32 + ic2] = h;
            w2s[(k * 2 + 1) * 1024 + oc2 * 32 + ic2] = l;
            float w3 = cw3[(oc2 * 32 + ic2) * 9 + k];
            _Float16 h3 = (_Float16)w3;
            _Float16 l3 = (_Float16)(w3 - (float)h3);
            w3s[(k * 2 + 0) * 1024 + oc2 * 32 + ic2] = h3;
            w3s[(k * 2 + 1) * 1024 + oc2 * 32 + ic2] = l3;
        }
    }
}

// ---------------- backbone: one block per image, 256 threads ----------------
// LDS (46640 B):
//   b1h/b1l: [256 px][32 ic] fp16, swizzled (16384 B each)
//   region2 (13872 B): sx [3][34][34] fp32 (conv1 input)  -- dead after conv1
//                      then b2h/b2l [64 px][32 ic] fp16 (4096 B each)
//                           + b3f [32][4][4] fp32 (2048 B)
// Activation swizzle: element = pix*32 + (((icgrp) + (pix_x>>1)) & 3)*8 + (ic&7)
//   (b1 uses x-coordinate for rotation; b2 uses linear pixel index)
__global__ __launch_bounds__(256, 3) void backbone_kernel(
    const float* __restrict__ x,
    const float* __restrict__ w1t, const float* __restrict__ cb1,
    const _Float16* __restrict__ w2s, const float* __restrict__ cb2,
    const _Float16* __restrict__ w3s, const float* __restrict__ cb3,
    const float* __restrict__ w4t, const float* __restrict__ cb4,
    float* __restrict__ t4)
{
    __shared__ __align__(16) unsigned char smem[46640];
    _Float16* b1h = (_Float16*)smem;                     // 16384 B
    _Float16* b1l = (_Float16*)(smem + 16384);           // 16384 B
    float*    sxf = (float*)(smem + 32768);              // 3468 floats
    _Float16* b2h = (_Float16*)(smem + 32768);           // 4096 B (aliases sx)
    _Float16* b2l = (_Float16*)(smem + 32768 + 4096);    // 4096 B
    float*    b3f = (float*)(smem + 32768 + 8192);       // 512 floats [oc][y*4+x]

    float (*sx)[34][34] = reinterpret_cast<float(*)[34][34]>(sxf);

    const int t = threadIdx.x;
    const int b = blockIdx.x;
    const int lane = t & 63;
    const int wv = __builtin_amdgcn_readfirstlane(t >> 6);  // wave id 0..3
    const int ocb = wv << 3;                                 // conv1/conv4 oc group
    const int xl = lane & 15;                                // MFMA n / A-row lane
    const int g  = lane >> 4;                                // MFMA k-group / D row grp

    // zero conv1 input region (halo needs zeros)
    for (int i = t; i < 3468; i += 256) sxf[i] = 0.f;
    __syncthreads();

    // load image into padded sx
    {
        const float* xb = x + (size_t)b * 3072;
        for (int i = t; i < 3072; i += 256) {
            int ic = i >> 10, r = i & 1023;
            sx[ic][(r >> 5) + 1][(r & 31) + 1] = xb[i];
        }
    }
    __syncthreads();

    // ---- conv1 (fp32 VALU): 3->32, 32x32, relu, pool -> b1 h/l fp16 ----
    {
        float bias[8];
        #pragma unroll
        for (int o = 0; o < 8; ++o) bias[o] = cb1[ocb + o];
        for (int q = 0; q < 4; ++q) {
            const int id = (q << 6) | lane;       // pooled pixel 0..255
            const int py = id >> 4, px = id & 15;
            float acc[2][2][8];
            #pragma unroll
            for (int sy = 0; sy < 2; ++sy)
                #pragma unroll
                for (int sxx = 0; sxx < 2; ++sxx)
                    #pragma unroll
                    for (int o = 0; o < 8; ++o) acc[sy][sxx][o] = bias[o];
            #pragma unroll
            for (int ic = 0; ic < 3; ++ic) {
                float wn[4][4];
                #pragma unroll
                for (int wy = 0; wy < 4; ++wy) {
                    const float2* rp = reinterpret_cast<const float2*>(&sx[ic][2 * py + wy][2 * px]);
                    float2 lo = rp[0], hi = rp[1];
                    wn[wy][0] = lo.x; wn[wy][1] = lo.y;
                    wn[wy][2] = hi.x; wn[wy][3] = hi.y;
                }
                const float* w = w1t + (ic * 32 + ocb) * 9;
                #pragma unroll
                for (int o = 0; o < 8; ++o) {
                    #pragma unroll
                    for (int dy = 0; dy < 3; ++dy)
                        #pragma unroll
                        for (int dx = 0; dx < 3; ++dx) {
                            const float wvv = w[o * 9 + dy * 3 + dx];
                            #pragma unroll
                            for (int sy = 0; sy < 2; ++sy)
                                #pragma unroll
                                for (int sxx = 0; sxx < 2; ++sxx)
                                    acc[sy][sxx][o] = fmaf(wvv, wn[sy + dy][sxx + dx], acc[sy][sxx][o]);
                        }
                }
            }
            f16x8 hv, lv;
            #pragma unroll
            for (int o = 0; o < 8; ++o) {
                float m = fmaxf(fmaxf(acc[0][0][o], acc[0][1][o]),
                                fmaxf(acc[1][0][o], acc[1][1][o]));
                float v = fmaxf(m, 0.f);
                _Float16 h = (_Float16)v;
                hv[o] = h;
                lv[o] = (_Float16)(v - (float)h);
            }
            const int pix = py * 16 + px;
            const int so = (wv + (px >> 1)) & 3;     // slot = wv (ocb>>3), rotated
            const int e = pix * 32 + so * 8;
            *reinterpret_cast<f16x8*>(b1h + e) = hv;
            *reinterpret_cast<f16x8*>(b1l + e) = lv;
        }
    }
    __syncthreads();

    // ---- conv2 (MFMA): 32->32, 16x16, relu, pool -> b2 h/l fp16 ----
    {
        const int aoff = xl * 32 + g * 8;   // A-frag lane offset within [oc][ic] block
        f32x4 acc[4][2];
        #pragma unroll
        for (int j = 0; j < 4; ++j)
            #pragma unroll
            for (int m = 0; m < 2; ++m)
                #pragma unroll
                for (int r = 0; r < 4; ++r) acc[j][m][r] = 0.f;

        #pragma unroll
        for (int dy = 0; dy < 3; ++dy) {
            #pragma unroll
            for (int dx = 0; dx < 3; ++dx) {
                const _Float16* wb = w2s + (dy * 3 + dx) * 2048;
                f16x8 ah0 = *reinterpret_cast<const f16x8*>(wb + aoff);          // h, m0
                f16x8 ah1 = *reinterpret_cast<const f16x8*>(wb + 512 + aoff);    // h, m1
                f16x8 al0 = *reinterpret_cast<const f16x8*>(wb + 1024 + aoff);   // l, m0
                f16x8 al1 = *reinterpret_cast<const f16x8*>(wb + 1536 + aoff);   // l, m1

                const int sxL = xl + dx - 1;
                const bool ok = ((unsigned)sxL < 16u);
                const int cx = sxL < 0 ? 0 : (sxL > 15 ? 15 : sxL);
                const int so = (g + (cx >> 1)) & 3;
                #pragma unroll
                for (int j = 0; j < 4; ++j) {
                    const int sy = 4 * wv + j + dy - 1;   // wave-uniform
                    if (sy >= 0 && sy < 16) {
                        const int e = (sy * 16 + cx) * 32 + so * 8;
                        f16x8 bh = *reinterpret_cast<const f16x8*>(b1h + e);
                        f16x8 bl = *reinterpret_cast<const f16x8*>(b1l + e);
                        if (!ok) { bh = f16x8_zero(); bl = f16x8_zero(); }
                        acc[j][0] = __builtin_amdgcn_mfma_f32_16x16x32_f16(ah0, bh, acc[j][0], 0, 0, 0);
                        acc[j][0] = __builtin_amdgcn_mfma_f32_16x16x32_f16(ah0, bl, acc[j][0], 0, 0, 0);
                        acc[j][0] = __builtin_amdgcn_mfma_f32_16x16x32_f16(al0, bh, acc[j][0], 0, 0, 0);
                        acc[j][1] = __builtin_amdgcn_mfma_f32_16x16x32_f16(ah1, bh, acc[j][1], 0, 0, 0);
                        acc[j][1] = __builtin_amdgcn_mfma_f32_16x16x32_f16(ah1, bl, acc[j][1], 0, 0, 0);
                        acc[j][1] = __builtin_amdgcn_mfma_f32_16x16x32_f16(al1, bh, acc[j][1], 0, 0, 0);
                    }
                }
            }
        }
        __syncthreads();   // everyone done reading b1 / (region2 free of sx readers)

        // epilogue: pool 2x2 + bias + relu, split to fp16 h/l, write b2
        f32x4 bias0 = *reinterpret_cast<const f32x4*>(cb2 + g * 4);
        f32x4 bias1 = *reinterpret_cast<const f32x4*>(cb2 + 16 + g * 4);
        #pragma unroll
        for (int pj = 0; pj < 2; ++pj) {
            #pragma unroll
            for (int m = 0; m < 2; ++m) {
                f32x4 vv;
                #pragma unroll
                for (int r = 0; r < 4; ++r) {
                    float v = fmaxf(acc[2 * pj][m][r], acc[2 * pj + 1][m][r]);
                    v = fmaxf(v, __shfl_xor(v, 1));
                    vv[r] = fmaxf(v + (m ? bias1[r] : bias0[r]), 0.f);
                }
                if ((lane & 1) == 0) {
                    const int pp = (2 * wv + pj) * 8 + (xl >> 1);   // pooled pixel 0..63
                    const int slot = m * 2 + (g >> 1);
                    const int so2 = (slot + (pp >> 1)) & 3;
                    const int e = pp * 32 + so2 * 8 + (g & 1) * 4;
                    f16x4 h4, l4;
                    #pragma unroll
                    for (int r = 0; r < 4; ++r) {
                        _Float16 h = (_Float16)vv[r];
                        h4[r] = h;
                        l4[r] = (_Float16)(vv[r] - (float)h);
                    }
                    *reinterpret_cast<f16x4*>(b2h + e) = h4;
                    *reinterpret_cast<f16x4*>(b2l + e) = l4;
                }
            }
        }
    }
    __syncthreads();

    // ---- conv3 (MFMA): 32->32, 8x8, relu, pool -> b3f fp32 [32][4][4] ----
    {
        const int aoff = xl * 32 + g * 8;
        const int p = wv * 16 + xl;          // pre-pool pixel 0..63
        const int py3 = p >> 3, px3 = p & 7;
        f32x4 acc[2];
        #pragma unroll
        for (int m = 0; m < 2; ++m)
            #pragma unroll
            for (int r = 0; r < 4; ++r) acc[m][r] = 0.f;

        #pragma unroll
        for (int dy = 0; dy < 3; ++dy) {
            #pragma unroll
            for (int dx = 0; dx < 3; ++dx) {
                const _Float16* wb = w3s + (dy * 3 + dx) * 2048;
                f16x8 ah0 = *reinterpret_cast<const f16x8*>(wb + aoff);
                f16x8 ah1 = *reinterpret_cast<const f16x8*>(wb + 512 + aoff);
                f16x8 al0 = *reinterpret_cast<const f16x8*>(wb + 1024 + aoff);
                f16x8 al1 = *reinterpret_cast<const f16x8*>(wb + 1536 + aoff);

                const int syL = py3 + dy - 1, sxL = px3 + dx - 1;
                const bool ok = ((unsigned)syL < 8u) && ((unsigned)sxL < 8u);
                const int cy = syL < 0 ? 0 : (syL > 7 ? 7 : syL);
                const int cx = sxL < 0 ? 0 : (sxL > 7 ? 7 : sxL);
                const int cp = cy * 8 + cx;
                const int so = (g + (cp >> 1)) & 3;
                const int e = cp * 32 + so * 8;
                f16x8 bh = *reinterpret_cast<const f16x8*>(b2h + e);
                f16x8 bl = *reinterpret_cast<const f16x8*>(b2l + e);
                if (!ok) { bh = f16x8_zero(); bl = f16x8_zero(); }
                acc[0] = __builtin_amdgcn_mfma_f32_16x16x32_f16(ah0, bh, acc[0], 0, 0, 0);
                acc[0] = __builtin_amdgcn_mfma_f32_16x16x32_f16(ah0, bl, acc[0], 0, 0, 0);
                acc[0] = __builtin_amdgcn_mfma_f32_16x16x32_f16(al0, bh, acc[0], 0, 0, 0);
                acc[1] = __builtin_amdgcn_mfma_f32_16x16x32_f16(ah1, bh, acc[1], 0, 0, 0);
                acc[1] = __builtin_amdgcn_mfma_f32_16x16x32_f16(ah1, bl, acc[1], 0, 0, 0);
                acc[1] = __builtin_amdgcn_mfma_f32_16x16x32_f16(al1, bh, acc[1], 0, 0, 0);
            }
        }

        // epilogue: pool 2x2 (x-pair lane^1, y-pair lane^8) + bias + relu
        f32x4 bias0 = *reinterpret_cast<const f32x4*>(cb3 + g * 4);
        f32x4 bias1 = *reinterpret_cast<const f32x4*>(cb3 + 16 + g * 4);
        #pragma unroll
        for (int m = 0; m < 2; ++m) {
            f32x4 vv;
            #pragma unroll
            for (int r = 0; r < 4; ++r) {
                float v = acc[m][r];
                v = fmaxf(v, __shfl_xor(v, 1));
                v = fmaxf(v, __shfl_xor(v, 8));
                vv[r] = fmaxf(v + (m ? bias1[r] : bias0[r]), 0.f);
            }
            if ((lane & 9) == 0) {     // x even, y even
                const int yr = wv;                 // pooled row
                const int xr = (xl & 7) >> 1;      // pooled col
                #pragma unroll
                for (int r = 0; r < 4; ++r)
                    b3f[(m * 16 + g * 4 + r) * 16 + yr * 4 + xr] = vv[r];
            }
        }
    }
    __syncthreads();

    // ---- conv4 (fp32 VALU): 32->32, 4x4, relu, pool -> t4[b][32][2][2] ----
    {
        const int g4 = lane >> 4;          // oc-pair group 0..3
        const int yy = (lane >> 2) & 3;    // pre-pool row
        const int xx = lane & 3;           // pre-pool col
        int ri[3], ci[3]; bool rok[3], cok[3];
        #pragma unroll
        for (int d = 0; d < 3; ++d) {
            int r = yy + d - 1; rok[d] = ((unsigned)r < 4u); ri[d] = r & 3;
            int c = xx + d - 1; cok[d] = ((unsigned)c < 4u); ci[d] = c & 3;
        }
        const int oc0 = ocb + 2 * g4;
        float acc0 = cb4[oc0], acc1 = cb4[oc0 + 1];
        for (int ic = 0; ic < 32; ++ic) {
            float wn[3][3];
            #pragma unroll
            for (int dy = 0; dy < 3; ++dy)
                #pragma unroll
                for (int dx = 0; dx < 3; ++dx)
                    wn[dy][dx] = (rok[dy] && cok[dx]) ? b3f[ic * 16 + ri[dy] * 4 + ci[dx]] : 0.f;
            const float* w = w4t + (ic * 32 + oc0) * 9;
            #pragma unroll
            for (int dy = 0; dy < 3; ++dy)
                #pragma unroll
                for (int dx = 0; dx < 3; ++dx) {
                    acc0 = fmaf(w[dy * 3 + dx],     wn[dy][dx], acc0);
                    acc1 = fmaf(w[9 + dy * 3 + dx], wn[dy][dx], acc1);
                }
        }
        float v0 = fmaxf(acc0, 0.f), v1 = fmaxf(acc1, 0.f);
        v0 = fmaxf(v0, __shfl_xor(v0, 1)); v0 = fmaxf(v0, __shfl_xor(v0, 4));
        v1 = fmaxf(v1, __shfl_xor(v1, 1)); v1 = fmaxf(v1, __shfl_xor(v1, 4));
        if (((xx | yy) & 1) == 0) {
            const int py = yy >> 1, px = xx >> 1;
            t4[(size_t)b * 128 + oc0 * 4 + py * 2 + px] = v0;
            t4[(size_t)b * 128 + (oc0 + 1) * 4 + py * 2 + px] = v1;
        }
    }
}

// ---------------- BN batch stats: one block per channel ----------------
__global__ __launch_bounds__(256) void bnstats_kernel(
    const float* __restrict__ t4, float* __restrict__ mus, float* __restrict__ rss)
{
    __shared__ double ssum[256];
    __shared__ double ssq[256];
    const int c = blockIdx.x, t = threadIdx.x;
    double s = 0.0, q = 0.0;
    for (int j = t; j < 16384; j += 256) {
        float v = t4[(size_t)(j >> 2) * 128 + c * 4 + (j & 3)];
        s += (double)v;
        q += (double)v * (double)v;
    }
    ssum[t] = s; ssq[t] = q;
    __syncthreads();
    for (int w = 128; w > 0; w >>= 1) {
        if (t < w) { ssum[t] += ssum[t + w]; ssq[t] += ssq[t + w]; }
        __syncthreads();
    }
    if (t == 0) {
        double mu = ssum[0] / 16384.0;
        double var = ssq[0] / 16384.0 - mu * mu;
        mus[c] = (float)mu;
        rss[c] = (float)(1.0 / sqrt(var + 1e-5));
    }
}

// ---------------- routing + expert MLP: one block (1 wave) per sample ------
__global__ __launch_bounds__(64) void routing_kernel(
    const float* __restrict__ t4, const float* __restrict__ mus,
    const float* __restrict__ rss,
    const float* __restrict__ bng, const float* __restrict__ bnb,
    const float* __restrict__ wpt, const float* __restrict__ wd1,
    const float* __restrict__ wd2, const float* __restrict__ wd3,
    const float* __restrict__ s1w, const float* __restrict__ s1b,
    const float* __restrict__ s2w, const float* __restrict__ s2b,
    const float* __restrict__ s3w, const float* __restrict__ s3b,
    float* __restrict__ out)
{
    __shared__ float f[128];
    __shared__ float h1s[48];
    __shared__ float h2s[48];
    __shared__ float tmp[16];
    __shared__ int act;
    const int t = threadIdx.x, b = blockIdx.x;

    for (int i = t; i < 128; i += 64) {
        int c = i >> 2;
        float v = t4[(size_t)b * 128 + i];
        f[i] = (v - mus[c]) * rss[c] * bng[c] + bnb[c];
    }
    __syncthreads();

    if (t < 10) {
        double a = 0.0;
        for (int k = 0; k < 128; ++k) a = fma((double)f[k], (double)wpt[k * 10 + t], a);
        tmp[t] = (float)a;
    }
    __syncthreads();
    if (t == 0) {
        int bi = 0; float bv = tmp[0];
        for (int i = 1; i < 10; ++i) if (tmp[i] > bv) { bv = tmp[i]; bi = i; }
        act = bi;
    }
    __syncthreads();
    const int agent = act;

    if (t < 16) {
        double a = 0.0;
        const float* w = wd1 + (size_t)agent * 128 * 16 + t;
        for (int k = 0; k < 128; ++k) a = fma((double)f[k], (double)w[k * 16], a);
        tmp[t] = (float)a;
    }
    __syncthreads();
    if (t == 0) {
        int bi = 0; float bv = tmp[0];
        for (int i = 1; i < 16; ++i) if (tmp[i] > bv) { bv = tmp[i]; bi = i; }
        act = bi;
    }
    __syncthreads();
    const int a1 = act;

    if (t < 48) {
        float a = s1b[a1 * 48 + t];
        const float* w = s1w + (size_t)a1 * 128 * 48 + t;
        for (int k = 0; k < 128; ++k) a = fmaf(f[k], w[k * 48], a);
        h1s[t] = fmaxf(a, 0.f);
    }
    __syncthreads();

    if (t < 16) {
        double a = 0.0;
        const float* w = wd2 + (size_t)agent * 48 * 16 + t;
        for (int k = 0; k < 48; ++k) a = fma((double)h1s[k], (double)w[k * 16], a);
        tmp[t] = (float)a;
    }
    __syncthreads();
    if (t == 0) {
        int bi = 0; float bv = tmp[0];
        for (int i = 1; i < 16; ++i) if (tmp[i] > bv) { bv = tmp[i]; bi = i; }
        act = bi;
    }
    __syncthreads();
    const int a2 = act;

    if (t < 48) {
        float a = s2b[a2 * 48 + t];
        const float* w = s2w + (size_t)a2 * 48 * 48 + t;
        for (int k = 0; k < 48; ++k) a = fmaf(h1s[k], w[k * 48], a);
        h2s[t] = fmaxf(a, 0.f);
    }
    __syncthreads();

    if (t < 16) {
        double a = 0.0;
        const float* w = wd3 + (size_t)agent * 48 * 16 + t;
        for (int k = 0; k < 48; ++k) a = fma((double)h2s[k], (double)w[k * 16], a);
        tmp[t] = (float)a;
    }
    __syncthreads();
    if (t == 0) {
        int bi = 0; float bv = tmp[0];
        for (int i = 1; i < 16; ++i) if (tmp[i] > bv) { bv = tmp[i]; bi = i; }
        act = bi;
    }
    __syncthreads();
    const int a3 = act;

    if (t < 10) {
        float a = s3b[a3 * 10 + t];
        const float* w = s3w + (size_t)a3 * 48 * 10 + t;
        for (int k = 0; k < 48; ++k) a = fmaf(h2s[k], w[k * 10], a);
        out[(size_t)b * 10 + t] = a;
    }
}

// ---------------------------------------------------------------------------
extern "C" void kernel_launch(void* const* d_in, const int* in_sizes, int n_in,
                              void* d_out, int out_size, void* d_ws, size_t ws_size,
                              hipStream_t stream)
{
    (void)in_sizes; (void)n_in; (void)out_size; (void)ws_size;

    const float* x   = (const float*)d_in[0];
    const float* cw1 = (const float*)d_in[2];
    const float* cb1 = (const float*)d_in[3];
    const float* cw2 = (const float*)d_in[4];
    const float* cb2 = (const float*)d_in[5];
    const float* cw3 = (const float*)d_in[6];
    const float* cb3 = (const float*)d_in[7];
    const float* cw4 = (const float*)d_in[8];
    const float* cb4 = (const float*)d_in[9];
    const float* bng = (const float*)d_in[10];
    const float* bnb = (const float*)d_in[11];
    const float* wpt = (const float*)d_in[12];
    const float* wd1 = (const float*)d_in[13];
    const float* wd2 = (const float*)d_in[14];
    const float* wd3 = (const float*)d_in[15];
    const float* s1w = (const float*)d_in[16];
    const float* s1b = (const float*)d_in[17];
    const float* s2w = (const float*)d_in[18];
    const float* s2b = (const float*)d_in[19];
    const float* s3w = (const float*)d_in[20];
    const float* s3b = (const float*)d_in[21];
    float* out = (float*)d_out;

    float* t4  = (float*)d_ws;                       // [4096][128]
    float* mus = t4 + (size_t)IMG_B * 128;           // 32
    float* rss = mus + 32;                           // 32
    float* w1t = rss + 32;                           // 864 (fp32, conv1 ic-major)
    float* w4t = w1t + 864;                          // 9216 (fp32, conv4 ic-major)
    _Float16* w2s = (_Float16*)(w4t + 9216);         // 18432 f16
    _Float16* w3s = w2s + 18432;                     // 18432 f16

    hipLaunchKernelGGL(twt_kernel, dim3(36), dim3(256), 0, stream,
                       cw1, cw2, cw3, cw4, w1t, w4t, w2s, w3s);
    hipLaunchKernelGGL(backbone_kernel, dim3(IMG_B), dim3(256), 0, stream,
                       x, w1t, cb1, w2s, cb2, w3s, cb3, w4t, cb4, t4);
    hipLaunchKernelGGL(bnstats_kernel, dim3(32), dim3(256), 0, stream, t4, mus, rss);
    hipLaunchKernelGGL(routing_kernel, dim3(IMG_B), dim3(64), 0, stream,
                       t4, mus, rss, bng, bnb, wpt, wd1, wd2, wd3,
                       s1w, s1b, s2w, s2b, s3w, s3b, out);
}

// Round 4
// 188.952 us; speedup vs baseline: 3.6514x; 1.4935x over previous
//
#include <hip/hip_runtime.h>
#include <math.h>

// ---------------------------------------------------------------------------
// RoutedAllFC round 4: ALL four convs on MFMA (fp16 2-way-split, 3 products).
//  - conv1: K=27 (3ic x 9taps, padded to 32) single-slice im2col GEMM,
//    B-frag gathered from padded fp16 h/l input planes.
//  - conv2: b1 column-padded [16][18][32ic] -> no per-element halo cndmask.
//  - conv3: unchanged MFMA, epilogue now writes padded fp16 h/l b3 [36][32].
//  - conv4: MFMA, taps split across the 4 waves, LDS partial reduction.
// ---------------------------------------------------------------------------

#define IMG_B 4096

typedef _Float16 f16x8 __attribute__((ext_vector_type(8)));
typedef _Float16 f16x4 __attribute__((ext_vector_type(4)));
typedef float    f32x4 __attribute__((ext_vector_type(4)));

__device__ inline f16x8 f16x8_zero() {
    f16x8 z;
    #pragma unroll
    for (int i = 0; i < 8; ++i) z[i] = (_Float16)0.f;
    return z;
}

// ---- weight prep: fp16 h/l split for all convs --------------------------
// w1s: [part][oc(32)][k(32)]  k = ic*9 + dy*3 + dx, k>=27 -> 0
// w2s/w3s/w4s: [tap][part][oc(32)][ic(32)]
__global__ __launch_bounds__(256) void twt_kernel(
    const float* __restrict__ cw1, const float* __restrict__ cw2,
    const float* __restrict__ cw3, const float* __restrict__ cw4,
    _Float16* __restrict__ w1s, _Float16* __restrict__ w2s,
    _Float16* __restrict__ w3s, _Float16* __restrict__ w4s)
{
    const int i = blockIdx.x * 256 + threadIdx.x;
    if (i < 2048) {
        const int p = i >> 10, rr = i & 1023;
        const int oc = rr >> 5, k = rr & 31;
        _Float16 val = (_Float16)0.f;
        if (k < 27) {
            float w = cw1[oc * 27 + k];     // [oc][ic][3][3] flat == oc*27 + k
            _Float16 h = (_Float16)w;
            val = p ? (_Float16)(w - (float)h) : h;
        }
        w1s[p * 1024 + oc * 32 + k] = val;
    }
    if (i < 9216) {
        const int k = i % 9, r = i / 9;
        const int ic2 = r & 31, oc2 = r >> 5;
        {
            float w = cw2[(oc2 * 32 + ic2) * 9 + k];
            _Float16 h = (_Float16)w;
            w2s[(k * 2 + 0) * 1024 + oc2 * 32 + ic2] = h;
            w2s[(k * 2 + 1) * 1024 + oc2 * 32 + ic2] = (_Float16)(w - (float)h);
        }
        {
            float w = cw3[(oc2 * 32 + ic2) * 9 + k];
            _Float16 h = (_Float16)w;
            w3s[(k * 2 + 0) * 1024 + oc2 * 32 + ic2] = h;
            w3s[(k * 2 + 1) * 1024 + oc2 * 32 + ic2] = (_Float16)(w - (float)h);
        }
        {
            float w = cw4[(oc2 * 32 + ic2) * 9 + k];
            _Float16 h = (_Float16)w;
            w4s[(k * 2 + 0) * 1024 + oc2 * 32 + ic2] = h;
            w4s[(k * 2 + 1) * 1024 + oc2 * 32 + ic2] = (_Float16)(w - (float)h);
        }
    }
}

// ---------------- backbone: one block per image, 256 threads ----------------
// LDS (50736 B):
//   b1h/b1l : [16 rows][18 cols][32 ic] fp16, col-padded, swizzled (18432 B ea)
//   region2 (13872 B), time-shared:
//     phase conv1: sxh/sxl [3][34][34] fp16 padded (6936 B each)
//     phase conv2+: b2h/b2l [64 px][32 ic] (4096 B ea),
//                   b3h/b3l [36 px][32 ic] padded (2304 B ea at +8192)
//     phase conv4: scr [4 waves][64 lanes][8] f32 partials (8192 B at +0)
// Swizzle: ic-group grp (8 ic) stored at slot (grp + (col>>1)) & 3.
__global__ __launch_bounds__(256, 3) void backbone_kernel(
    const float* __restrict__ x,
    const _Float16* __restrict__ w1s, const float* __restrict__ cb1,
    const _Float16* __restrict__ w2s, const float* __restrict__ cb2,
    const _Float16* __restrict__ w3s, const float* __restrict__ cb3,
    const _Float16* __restrict__ w4s, const float* __restrict__ cb4,
    float* __restrict__ t4)
{
    __shared__ __align__(16) unsigned char smem[50736];
    _Float16* b1h = (_Float16*)smem;                    // 18432 B
    _Float16* b1l = (_Float16*)(smem + 18432);          // 18432 B
    unsigned char* region2 = smem + 36864;              // 13872 B
    _Float16* sxh = (_Float16*)region2;                 // 3468 el
    _Float16* sxl = (_Float16*)(region2 + 6936);        // 3468 el
    _Float16* b2h = (_Float16*)region2;                 // 2048 el
    _Float16* b2l = (_Float16*)(region2 + 4096);        // 2048 el
    _Float16* b3h = (_Float16*)(region2 + 8192);        // 1152 el
    _Float16* b3l = (_Float16*)(region2 + 10496);       // 1152 el
    float*    scr = (float*)region2;                    // 2048 f32

    const int t = threadIdx.x;
    const int b = blockIdx.x;
    const int lane = t & 63;
    const int wv = __builtin_amdgcn_readfirstlane(t >> 6);  // wave id 0..3
    const int xl = lane & 15;                                // MFMA col lane
    const int g  = lane >> 4;                                // MFMA k-group
    const int aoff = xl * 32 + g * 8;                        // A-frag offset in [oc][32]

    // ---- init: zero region2 (sx halos) + b1 halo columns (c=0,17) ----
    {
        unsigned* r2w = (unsigned*)region2;
        for (int i = t; i < 3468; i += 256) r2w[i] = 0;
        for (int i = t; i < 1024; i += 256) {
            const int j = i & 15, cs = (i >> 4) & 1, r = (i >> 5) & 15, P = i >> 9;
            ((unsigned*)(smem + P * 18432))[(r * 18 + (cs ? 17 : 0)) * 16 + j] = 0;
        }
    }
    __syncthreads();

    // ---- load image, split to fp16 h/l padded planes ----
    {
        const float* xb = x + (size_t)b * 3072;
        for (int i = t; i < 3072; i += 256) {
            const int ic = i >> 10, r = i & 1023;
            const float v = xb[i];
            const _Float16 h = (_Float16)v;
            const int o = ic * 1156 + ((r >> 5) + 1) * 34 + (r & 31) + 1;
            sxh[o] = h;
            sxl[o] = (_Float16)(v - (float)h);
        }
    }
    __syncthreads();

    // ---- conv1 (MFMA, K=27 pad 32): 3->32, 32x32, relu, pool -> b1 ----
    {
        // A-frags (weights), held in registers
        const f16x8 ah0 = *(const f16x8*)(w1s + xl * 32 + g * 8);
        const f16x8 ah1 = *(const f16x8*)(w1s + (16 + xl) * 32 + g * 8);
        const f16x8 al0 = *(const f16x8*)(w1s + 1024 + xl * 32 + g * 8);
        const f16x8 al1 = *(const f16x8*)(w1s + 1024 + (16 + xl) * 32 + g * 8);
        const f32x4 cbias0 = *(const f32x4*)(cb1 + g * 4);
        const f32x4 cbias1 = *(const f32x4*)(cb1 + 16 + g * 4);

        // per-lane gather offsets for the 8 k's of this lane's k-group
        int off_j[8];
        #pragma unroll
        for (int j = 0; j < 8; ++j) {
            int k = g * 8 + j; if (k > 26) k = 26;   // padded k: A is 0 there
            const int ic = k / 9, t9 = k - ic * 9;
            const int dy = t9 / 3, dx = t9 - dy * 3;
            off_j[j] = ic * 1156 + dy * 34 + dx;
        }

        for (int q = 0; q < 4; ++q) {
            const int rp = wv * 4 + q;          // pooled row 0..15
            const int y0 = 2 * rp;              // pre-pool rows y0, y0+1
            for (int xt = 0; xt < 2; ++xt) {
                const int xpix = xt * 16 + xl;
                f32x4 acc[2][2];
                #pragma unroll
                for (int yy = 0; yy < 2; ++yy)
                    #pragma unroll
                    for (int m = 0; m < 2; ++m)
                        #pragma unroll
                        for (int r = 0; r < 4; ++r) acc[yy][m][r] = 0.f;
                #pragma unroll
                for (int yy = 0; yy < 2; ++yy) {
                    const int base = (y0 + yy) * 34 + xpix;
                    f16x8 bh, bl;
                    #pragma unroll
                    for (int j = 0; j < 8; ++j) {
                        const int o = off_j[j] + base;
                        bh[j] = sxh[o];
                        bl[j] = sxl[o];
                    }
                    acc[yy][0] = __builtin_amdgcn_mfma_f32_16x16x32_f16(ah0, bh, acc[yy][0], 0, 0, 0);
                    acc[yy][0] = __builtin_amdgcn_mfma_f32_16x16x32_f16(ah0, bl, acc[yy][0], 0, 0, 0);
                    acc[yy][0] = __builtin_amdgcn_mfma_f32_16x16x32_f16(al0, bh, acc[yy][0], 0, 0, 0);
                    acc[yy][1] = __builtin_amdgcn_mfma_f32_16x16x32_f16(ah1, bh, acc[yy][1], 0, 0, 0);
                    acc[yy][1] = __builtin_amdgcn_mfma_f32_16x16x32_f16(ah1, bl, acc[yy][1], 0, 0, 0);
                    acc[yy][1] = __builtin_amdgcn_mfma_f32_16x16x32_f16(al1, bh, acc[yy][1], 0, 0, 0);
                }
                // pool(y-pair in regs, x-pair via shfl) + bias + relu -> b1
                #pragma unroll
                for (int m = 0; m < 2; ++m) {
                    f32x4 vv;
                    #pragma unroll
                    for (int r = 0; r < 4; ++r) {
                        float v = fmaxf(acc[0][m][r], acc[1][m][r]);
                        v = fmaxf(v, __shfl_xor(v, 1));
                        vv[r] = fmaxf(v + (m ? cbias1[r] : cbias0[r]), 0.f);
                    }
                    if ((xl & 1) == 0) {
                        const int c = xt * 8 + (xl >> 1) + 1;     // storage col 1..16
                        const int grp = m * 2 + (g >> 1);
                        const int so = (grp + (c >> 1)) & 3;
                        const int e = (rp * 18 + c) * 32 + so * 8 + (g & 1) * 4;
                        f16x4 h4, l4;
                        #pragma unroll
                        for (int r = 0; r < 4; ++r) {
                            const _Float16 h = (_Float16)vv[r];
                            h4[r] = h;
                            l4[r] = (_Float16)(vv[r] - (float)h);
                        }
                        *(f16x4*)(b1h + e) = h4;
                        *(f16x4*)(b1l + e) = l4;
                    }
                }
            }
        }
    }
    __syncthreads();

    // ---- conv2 (MFMA): 32->32, 16x16, relu, pool -> b2 ----
    {
        // zero b3 region (aliases dead sx tail); used two phases later
        for (int i = t; i < 1152; i += 256) ((unsigned*)(region2 + 8192))[i] = 0;

        f32x4 acc[4][2];
        #pragma unroll
        for (int j = 0; j < 4; ++j)
            #pragma unroll
            for (int m = 0; m < 2; ++m)
                #pragma unroll
                for (int r = 0; r < 4; ++r) acc[j][m][r] = 0.f;

        #pragma unroll
        for (int dy = 0; dy < 3; ++dy) {
            #pragma unroll
            for (int dx = 0; dx < 3; ++dx) {
                const _Float16* wb = w2s + (dy * 3 + dx) * 2048;
                const f16x8 ah0 = *(const f16x8*)(wb + aoff);
                const f16x8 ah1 = *(const f16x8*)(wb + 512 + aoff);
                const f16x8 al0 = *(const f16x8*)(wb + 1024 + aoff);
                const f16x8 al1 = *(const f16x8*)(wb + 1536 + aoff);

                const int cxs = xl + dx;                  // storage col 0..17
                const int so = (g + (cxs >> 1)) & 3;
                #pragma unroll
                for (int j = 0; j < 4; ++j) {
                    const int sy = 4 * wv + j + dy - 1;   // wave-uniform
                    if ((unsigned)sy < 16u) {
                        const int e = (sy * 18 + cxs) * 32 + so * 8;
                        const f16x8 bh = *(const f16x8*)(b1h + e);
                        const f16x8 bl = *(const f16x8*)(b1l + e);
                        acc[j][0] = __builtin_amdgcn_mfma_f32_16x16x32_f16(ah0, bh, acc[j][0], 0, 0, 0);
                        acc[j][0] = __builtin_amdgcn_mfma_f32_16x16x32_f16(ah0, bl, acc[j][0], 0, 0, 0);
                        acc[j][0] = __builtin_amdgcn_mfma_f32_16x16x32_f16(al0, bh, acc[j][0], 0, 0, 0);
                        acc[j][1] = __builtin_amdgcn_mfma_f32_16x16x32_f16(ah1, bh, acc[j][1], 0, 0, 0);
                        acc[j][1] = __builtin_amdgcn_mfma_f32_16x16x32_f16(ah1, bl, acc[j][1], 0, 0, 0);
                        acc[j][1] = __builtin_amdgcn_mfma_f32_16x16x32_f16(al1, bh, acc[j][1], 0, 0, 0);
                    }
                }
            }
        }

        // epilogue: pool 2x2 + bias + relu, split fp16 h/l -> b2 [64px][32ic]
        const f32x4 bias0 = *(const f32x4*)(cb2 + g * 4);
        const f32x4 bias1 = *(const f32x4*)(cb2 + 16 + g * 4);
        #pragma unroll
        for (int pj = 0; pj < 2; ++pj) {
            #pragma unroll
            for (int m = 0; m < 2; ++m) {
                f32x4 vv;
                #pragma unroll
                for (int r = 0; r < 4; ++r) {
                    float v = fmaxf(acc[2 * pj][m][r], acc[2 * pj + 1][m][r]);
                    v = fmaxf(v, __shfl_xor(v, 1));
                    vv[r] = fmaxf(v + (m ? bias1[r] : bias0[r]), 0.f);
                }
                if ((lane & 1) == 0) {
                    const int pp = (2 * wv + pj) * 8 + (xl >> 1);   // pooled px 0..63
                    const int slot = m * 2 + (g >> 1);
                    const int so2 = (slot + (pp >> 1)) & 3;
                    const int e = pp * 32 + so2 * 8 + (g & 1) * 4;
                    f16x4 h4, l4;
                    #pragma unroll
                    for (int r = 0; r < 4; ++r) {
                        const _Float16 h = (_Float16)vv[r];
                        h4[r] = h;
                        l4[r] = (_Float16)(vv[r] - (float)h);
                    }
                    *(f16x4*)(b2h + e) = h4;
                    *(f16x4*)(b2l + e) = l4;
                }
            }
        }
    }
    __syncthreads();

    // ---- conv3 (MFMA): 32->32, 8x8, relu, pool -> b3 padded [36px][32ic] ----
    {
        const int p = wv * 16 + xl;          // pre-pool pixel 0..63
        const int py3 = p >> 3, px3 = p & 7;
        f32x4 acc[2];
        #pragma unroll
        for (int m = 0; m < 2; ++m)
            #pragma unroll
            for (int r = 0; r < 4; ++r) acc[m][r] = 0.f;

        #pragma unroll
        for (int dy = 0; dy < 3; ++dy) {
            #pragma unroll
            for (int dx = 0; dx < 3; ++dx) {
                const _Float16* wb = w3s + (dy * 3 + dx) * 2048;
                const f16x8 ah0 = *(const f16x8*)(wb + aoff);
                const f16x8 ah1 = *(const f16x8*)(wb + 512 + aoff);
                const f16x8 al0 = *(const f16x8*)(wb + 1024 + aoff);
                const f16x8 al1 = *(const f16x8*)(wb + 1536 + aoff);

                const int syL = py3 + dy - 1, sxL = px3 + dx - 1;
                const bool ok = ((unsigned)syL < 8u) && ((unsigned)sxL < 8u);
                const int cy = syL < 0 ? 0 : (syL > 7 ? 7 : syL);
                const int cx = sxL < 0 ? 0 : (sxL > 7 ? 7 : sxL);
                const int cp = cy * 8 + cx;
                const int so = (g + (cp >> 1)) & 3;
                const int e = cp * 32 + so * 8;
                f16x8 bh = *(const f16x8*)(b2h + e);
                f16x8 bl = *(const f16x8*)(b2l + e);
                if (!ok) { bh = f16x8_zero(); bl = f16x8_zero(); }
                acc[0] = __builtin_amdgcn_mfma_f32_16x16x32_f16(ah0, bh, acc[0], 0, 0, 0);
                acc[0] = __builtin_amdgcn_mfma_f32_16x16x32_f16(ah0, bl, acc[0], 0, 0, 0);
                acc[0] = __builtin_amdgcn_mfma_f32_16x16x32_f16(al0, bh, acc[0], 0, 0, 0);
                acc[1] = __builtin_amdgcn_mfma_f32_16x16x32_f16(ah1, bh, acc[1], 0, 0, 0);
                acc[1] = __builtin_amdgcn_mfma_f32_16x16x32_f16(ah1, bl, acc[1], 0, 0, 0);
                acc[1] = __builtin_amdgcn_mfma_f32_16x16x32_f16(al1, bh, acc[1], 0, 0, 0);
            }
        }

        // epilogue: pool + bias + relu, split fp16 h/l -> padded b3
        const f32x4 bias0 = *(const f32x4*)(cb3 + g * 4);
        const f32x4 bias1 = *(const f32x4*)(cb3 + 16 + g * 4);
        #pragma unroll
        for (int m = 0; m < 2; ++m) {
            f32x4 vv;
            #pragma unroll
            for (int r = 0; r < 4; ++r) {
                float v = acc[m][r];
                v = fmaxf(v, __shfl_xor(v, 1));
                v = fmaxf(v, __shfl_xor(v, 8));
                vv[r] = fmaxf(v + (m ? bias1[r] : bias0[r]), 0.f);
            }
            if ((lane & 9) == 0) {     // x even, y even
                const int yr = wv;                 // pooled row 0..3
                const int xr = (xl & 7) >> 1;      // pooled col 0..3
                const int pp3 = (yr + 1) * 6 + (xr + 1);   // padded px
                const int grp = m * 2 + (g >> 1);
                const int so = (grp + (pp3 >> 1)) & 3;
                const int e = pp3 * 32 + so * 8 + (g & 1) * 4;
                f16x4 h4, l4;
                #pragma unroll
                for (int r = 0; r < 4; ++r) {
                    const _Float16 h = (_Float16)vv[r];
                    h4[r] = h;
                    l4[r] = (_Float16)(vv[r] - (float)h);
                }
                *(f16x4*)(b3h + e) = h4;
                *(f16x4*)(b3l + e) = l4;
            }
        }
    }
    __syncthreads();

    // ---- conv4 (MFMA, taps split across waves): -> t4[b][32][2][2] ----
    {
        f32x4 a4[2];
        #pragma unroll
        for (int m = 0; m < 2; ++m)
            #pragma unroll
            for (int r = 0; r < 4; ++r) a4[m][r] = 0.f;

        for (int t9 = wv; t9 < 9; t9 += 4) {         // wave0:{0,4,8} etc.
            const _Float16* wb = w4s + t9 * 2048;
            const f16x8 ah0 = *(const f16x8*)(wb + aoff);
            const f16x8 ah1 = *(const f16x8*)(wb + 512 + aoff);
            const f16x8 al0 = *(const f16x8*)(wb + 1024 + aoff);
            const f16x8 al1 = *(const f16x8*)(wb + 1536 + aoff);
            const int dy = t9 / 3, dx = t9 - dy * 3;
            const int pp3 = ((xl >> 2) + dy) * 6 + (xl & 3) + dx;  // padded, in-range
            const int so = (g + (pp3 >> 1)) & 3;
            const int e = pp3 * 32 + so * 8;
            const f16x8 bh = *(const f16x8*)(b3h + e);
            const f16x8 bl = *(const f16x8*)(b3l + e);
            a4[0] = __builtin_amdgcn_mfma_f32_16x16x32_f16(ah0, bh, a4[0], 0, 0, 0);
            a4[0] = __builtin_amdgcn_mfma_f32_16x16x32_f16(ah0, bl, a4[0], 0, 0, 0);
            a4[0] = __builtin_amdgcn_mfma_f32_16x16x32_f16(al0, bh, a4[0], 0, 0, 0);
            a4[1] = __builtin_amdgcn_mfma_f32_16x16x32_f16(ah1, bh, a4[1], 0, 0, 0);
            a4[1] = __builtin_amdgcn_mfma_f32_16x16x32_f16(ah1, bl, a4[1], 0, 0, 0);
            a4[1] = __builtin_amdgcn_mfma_f32_16x16x32_f16(al1, bh, a4[1], 0, 0, 0);
        }
        // write partials (reuses dead b2 region)
        const int off = (wv * 64 + lane) * 8;
        *(f32x4*)(scr + off) = a4[0];
        *(f32x4*)(scr + off + 4) = a4[1];
        __syncthreads();

        // reduce across waves + bias + relu + pool + store
        f32x4 r0, r1;
        #pragma unroll
        for (int r = 0; r < 4; ++r) { r0[r] = 0.f; r1[r] = 0.f; }
        #pragma unroll
        for (int w = 0; w < 4; ++w) {
            const f32x4 p0 = *(const f32x4*)(scr + (w * 64 + lane) * 8);
            const f32x4 p1 = *(const f32x4*)(scr + (w * 64 + lane) * 8 + 4);
            #pragma unroll
            for (int r = 0; r < 4; ++r) { r0[r] += p0[r]; r1[r] += p1[r]; }
        }
        const f32x4 bias0 = *(const f32x4*)(cb4 + g * 4);
        const f32x4 bias1 = *(const f32x4*)(cb4 + 16 + g * 4);
        const int y = xl >> 2, xx = xl & 3;
        #pragma unroll
        for (int m = 0; m < 2; ++m) {
            f32x4 vv;
            #pragma unroll
            for (int r = 0; r < 4; ++r) {
                float v = m ? r1[r] : r0[r];
                v = fmaxf(v, __shfl_xor(v, 1));
                v = fmaxf(v, __shfl_xor(v, 4));
                vv[r] = fmaxf(v + (m ? bias1[r] : bias0[r]), 0.f);
            }
            if ((xl & 5) == 0) {       // x even, y even
                const int oc0 = m * 16 + g * 4;
                #pragma unroll
                for (int r = 0; r < 4; ++r)
                    t4[(size_t)b * 128 + (oc0 + r) * 4 + (y >> 1) * 2 + (xx >> 1)] = vv[r];
            }
        }
    }
}

// ---------------- BN batch stats: one block per channel ----------------
__global__ __launch_bounds__(256) void bnstats_kernel(
    const float* __restrict__ t4, float* __restrict__ mus, float* __restrict__ rss)
{
    __shared__ double ssum[256];
    __shared__ double ssq[256];
    const int c = blockIdx.x, t = threadIdx.x;
    double s = 0.0, q = 0.0;
    for (int j = t; j < 16384; j += 256) {
        float v = t4[(size_t)(j >> 2) * 128 + c * 4 + (j & 3)];
        s += (double)v;
        q += (double)v * (double)v;
    }
    ssum[t] = s; ssq[t] = q;
    __syncthreads();
    for (int w = 128; w > 0; w >>= 1) {
        if (t < w) { ssum[t] += ssum[t + w]; ssq[t] += ssq[t + w]; }
        __syncthreads();
    }
    if (t == 0) {
        double mu = ssum[0] / 16384.0;
        double var = ssq[0] / 16384.0 - mu * mu;
        mus[c] = (float)mu;
        rss[c] = (float)(1.0 / sqrt(var + 1e-5));
    }
}

// ---------------- routing + expert MLP: one block (1 wave) per sample ------
__global__ __launch_bounds__(64) void routing_kernel(
    const float* __restrict__ t4, const float* __restrict__ mus,
    const float* __restrict__ rss,
    const float* __restrict__ bng, const float* __restrict__ bnb,
    const float* __restrict__ wpt, const float* __restrict__ wd1,
    const float* __restrict__ wd2, const float* __restrict__ wd3,
    const float* __restrict__ s1w, const float* __restrict__ s1b,
    const float* __restrict__ s2w, const float* __restrict__ s2b,
    const float* __restrict__ s3w, const float* __restrict__ s3b,
    float* __restrict__ out)
{
    __shared__ float f[128];
    __shared__ float h1s[48];
    __shared__ float h2s[48];
    __shared__ float tmp[16];
    __shared__ int act;
    const int t = threadIdx.x, b = blockIdx.x;

    for (int i = t; i < 128; i += 64) {
        int c = i >> 2;
        float v = t4[(size_t)b * 128 + i];
        f[i] = (v - mus[c]) * rss[c] * bng[c] + bnb[c];
    }
    __syncthreads();

    if (t < 10) {
        double a = 0.0;
        for (int k = 0; k < 128; ++k) a = fma((double)f[k], (double)wpt[k * 10 + t], a);
        tmp[t] = (float)a;
    }
    __syncthreads();
    if (t == 0) {
        int bi = 0; float bv = tmp[0];
        for (int i = 1; i < 10; ++i) if (tmp[i] > bv) { bv = tmp[i]; bi = i; }
        act = bi;
    }
    __syncthreads();
    const int agent = act;

    if (t < 16) {
        double a = 0.0;
        const float* w = wd1 + (size_t)agent * 128 * 16 + t;
        for (int k = 0; k < 128; ++k) a = fma((double)f[k], (double)w[k * 16], a);
        tmp[t] = (float)a;
    }
    __syncthreads();
    if (t == 0) {
        int bi = 0; float bv = tmp[0];
        for (int i = 1; i < 16; ++i) if (tmp[i] > bv) { bv = tmp[i]; bi = i; }
        act = bi;
    }
    __syncthreads();
    const int a1 = act;

    if (t < 48) {
        float a = s1b[a1 * 48 + t];
        const float* w = s1w + (size_t)a1 * 128 * 48 + t;
        for (int k = 0; k < 128; ++k) a = fmaf(f[k], w[k * 48], a);
        h1s[t] = fmaxf(a, 0.f);
    }
    __syncthreads();

    if (t < 16) {
        double a = 0.0;
        const float* w = wd2 + (size_t)agent * 48 * 16 + t;
        for (int k = 0; k < 48; ++k) a = fma((double)h1s[k], (double)w[k * 16], a);
        tmp[t] = (float)a;
    }
    __syncthreads();
    if (t == 0) {
        int bi = 0; float bv = tmp[0];
        for (int i = 1; i < 16; ++i) if (tmp[i] > bv) { bv = tmp[i]; bi = i; }
        act = bi;
    }
    __syncthreads();
    const int a2 = act;

    if (t < 48) {
        float a = s2b[a2 * 48 + t];
        const float* w = s2w + (size_t)a2 * 48 * 48 + t;
        for (int k = 0; k < 48; ++k) a = fmaf(h1s[k], w[k * 48], a);
        h2s[t] = fmaxf(a, 0.f);
    }
    __syncthreads();

    if (t < 16) {
        double a = 0.0;
        const float* w = wd3 + (size_t)agent * 48 * 16 + t;
        for (int k = 0; k < 48; ++k) a = fma((double)h2s[k], (double)w[k * 16], a);
        tmp[t] = (float)a;
    }
    __syncthreads();
    if (t == 0) {
        int bi = 0; float bv = tmp[0];
        for (int i = 1; i < 16; ++i) if (tmp[i] > bv) { bv = tmp[i]; bi = i; }
        act = bi;
    }
    __syncthreads();
    const int a3 = act;

    if (t < 10) {
        float a = s3b[a3 * 10 + t];
        const float* w = s3w + (size_t)a3 * 48 * 10 + t;
        for (int k = 0; k < 48; ++k) a = fmaf(h2s[k], w[k * 10], a);
        out[(size_t)b * 10 + t] = a;
    }
}

// ---------------------------------------------------------------------------
extern "C" void kernel_launch(void* const* d_in, const int* in_sizes, int n_in,
                              void* d_out, int out_size, void* d_ws, size_t ws_size,
                              hipStream_t stream)
{
    (void)in_sizes; (void)n_in; (void)out_size; (void)ws_size;

    const float* x   = (const float*)d_in[0];
    const float* cw1 = (const float*)d_in[2];
    const float* cb1 = (const float*)d_in[3];
    const float* cw2 = (const float*)d_in[4];
    const float* cb2 = (const float*)d_in[5];
    const float* cw3 = (const float*)d_in[6];
    const float* cb3 = (const float*)d_in[7];
    const float* cw4 = (const float*)d_in[8];
    const float* cb4 = (const float*)d_in[9];
    const float* bng = (const float*)d_in[10];
    const float* bnb = (const float*)d_in[11];
    const float* wpt = (const float*)d_in[12];
    const float* wd1 = (const float*)d_in[13];
    const float* wd2 = (const float*)d_in[14];
    const float* wd3 = (const float*)d_in[15];
    const float* s1w = (const float*)d_in[16];
    const float* s1b = (const float*)d_in[17];
    const float* s2w = (const float*)d_in[18];
    const float* s2b = (const float*)d_in[19];
    const float* s3w = (const float*)d_in[20];
    const float* s3b = (const float*)d_in[21];
    float* out = (float*)d_out;

    float* t4  = (float*)d_ws;                       // [4096][128]
    float* mus = t4 + (size_t)IMG_B * 128;           // 32
    float* rss = mus + 32;                           // 32
    _Float16* w1s = (_Float16*)(rss + 32);           // 2048 f16
    _Float16* w2s = w1s + 2048;                      // 18432 f16
    _Float16* w3s = w2s + 18432;                     // 18432 f16
    _Float16* w4s = w3s + 18432;                     // 18432 f16

    hipLaunchKernelGGL(twt_kernel, dim3(36), dim3(256), 0, stream,
                       cw1, cw2, cw3, cw4, w1s, w2s, w3s, w4s);
    hipLaunchKernelGGL(backbone_kernel, dim3(IMG_B), dim3(256), 0, stream,
                       x, w1s, cb1, w2s, cb2, w3s, cb3, w4s, cb4, t4);
    hipLaunchKernelGGL(bnstats_kernel, dim3(32), dim3(256), 0, stream, t4, mus, rss);
    hipLaunchKernelGGL(routing_kernel, dim3(IMG_B), dim3(64), 0, stream,
                       t4, mus, rss, bng, bnb, wpt, wd1, wd2, wd3,
                       s1w, s1b, s2w, s2b, s3w, s3b, out);
}